// Round 7
// baseline (3414.994 us; speedup 1.0000x reference)
//
#include <hip/hip_runtime.h>
#include <math.h>

#define P    13
#define PP   169
#define NIMG 4
#define HIMG 256
#define HP   280            // 256 + 2*12
#define HO   268            // 280 - 13 + 1
#define NSH  4              // num shards

typedef __attribute__((ext_vector_type(8))) short short8_t;
typedef __attribute__((ext_vector_type(4))) float f32x4;

__device__ __forceinline__ ushort f2bf(float x) {
    union { float f; unsigned u; } a; a.f = x;
    unsigned r = a.u + 0x7fffu + ((a.u >> 16) & 1u);   // RNE
    return (ushort)(r >> 16);
}
__device__ __forceinline__ float bf2f(ushort b) {
    union { float f; unsigned u; } a; a.u = ((unsigned)b) << 16;
    return a.f;
}

// ---------------- prep1: Pm1 -> MFMA frag layout (plain K), split bf16 hi/lo (verified) ----------------
__global__ __launch_bounds__(256) void prep1_kernel(const float* __restrict__ Pm1,
                                                    ushort* __restrict__ prep1) {
    int idx = blockIdx.x*256 + threadIdx.x;
    if (idx >= 6*11*512) return;
    int j    = idx & 7;
    int lane = (idx >> 3) & 63;
    int rest = idx >> 9;
    int mt   = rest % 11;
    int ks   = rest / 11;
    int row  = mt*16 + (lane & 15);
    int k    = ks*32 + 8*(lane>>4) + j;
    float val = (row < PP && k < PP) ? Pm1[row*PP + k] : 0.0f;
    ushort h = f2bf(val);
    ushort lo = f2bf(val - bf2f(h));
    prep1[((ks*2+0)*11 + mt)*512 + lane*8 + j] = h;
    prep1[((ks*2+1)*11 + mt)*512 + lane*8 + j] = lo;
}

// ---------------- invert: row-per-thread Gauss-Jordan, k-loop FULLY UNROLLED ----------------
// 192 threads (3 waves). Thread i owns physical row i in registers (row[169]).
// Implicit pivoting: rows never move; explicit-swap world simulated via pos maps
// (tid 0 bookkeeping) and replayed as column swaps at writeout.
__global__ __launch_bounds__(192, 1) void invert_kernel(const float* __restrict__ Pm1,
                                                        ushort* __restrict__ prep2) {
    extern __shared__ float sm[];
    float* Adump = sm;                                 // 169*172 = 29068 f
    float* srow  = sm + 29068;                         // 176 f
    float* pvS   = sm + 29244;                         // 4 f (use [0])
    unsigned* partial = (unsigned*)(sm + 29248);       // 4 u
    int* perm_expl    = (int*)(sm + 29252);            // 169
    int* pos_of_phys  = (int*)(sm + 29421);            // 169
    int* phys_at_pos  = (int*)(sm + 29590);            // 169  (end 29759)

    int tid = threadIdx.x;
    bool isrow = (tid < PP);
    bool alive = isrow;

    float row[PP];
    {
        const float* src = Pm1 + (isrow ? tid*PP : 0);
#pragma unroll
        for (int u = 0; u < PP; ++u) row[u] = isrow ? src[u] : 0.0f;
    }
    if (tid < PP) { pos_of_phys[tid] = tid; phys_at_pos[tid] = tid; }
    __syncthreads();

#pragma unroll
    for (int k = 0; k < PP; ++k) {
        // pivot key from row[k] (compile-time index)
        unsigned key = 0u;
        if (alive) key = (__float_as_uint(fabsf(row[k])) & 0xFFFFFF00u) | (unsigned)(255 - tid);
#pragma unroll
        for (int m = 1; m < 64; m <<= 1) {
            unsigned o = __shfl_xor(key, m);
            key = (o > key) ? o : key;
        }
        if ((tid & 63) == 0) partial[tid >> 6] = key;
        __syncthreads();   // B1: partials visible
        unsigned kk = partial[0];
        { unsigned t1 = partial[1]; kk = (t1 > kk) ? t1 : kk;
          unsigned t2 = partial[2]; kk = (t2 > kk) ? t2 : kk; }
        int p = 255 - (int)(kk & 0xFFu);
        if (tid == p) {
            alive = false;
            pvS[0] = row[k];
#pragma unroll
            for (int u4 = 0; u4 < 42; ++u4) {
                float4 v; v.x = row[4*u4]; v.y = row[4*u4+1]; v.z = row[4*u4+2]; v.w = row[4*u4+3];
                *reinterpret_cast<float4*>(&srow[4*u4]) = v;
            }
            srow[168] = row[168];
        }
        if (tid == 0) {
            int q  = pos_of_phys[p]; perm_expl[k] = q;
            int rk = phys_at_pos[k];
            phys_at_pos[k] = p; phys_at_pos[q] = rk;
            pos_of_phys[p] = k; pos_of_phys[rk] = q;
        }
        __syncthreads();   // B2: srow + pv visible
        float invpv = 1.0f / pvS[0];
        if (tid == p) {
#pragma unroll
            for (int u = 0; u < PP; ++u) row[u] *= invpv;
            row[k] = invpv;
        } else {
            float dp = row[k] * invpv;
#pragma unroll
            for (int u4 = 0; u4 < 42; ++u4) {
                float4 s4 = *reinterpret_cast<float4*>(&srow[4*u4]);
                row[4*u4+0] = __builtin_fmaf(-dp, s4.x, row[4*u4+0]);
                row[4*u4+1] = __builtin_fmaf(-dp, s4.y, row[4*u4+1]);
                row[4*u4+2] = __builtin_fmaf(-dp, s4.z, row[4*u4+2]);
                row[4*u4+3] = __builtin_fmaf(-dp, s4.w, row[4*u4+3]);
            }
            row[168] = __builtin_fmaf(-dp, srow[168], row[168]);
            row[k] = -dp;
        }
    }
    __syncthreads();

    // dump rows at their explicit-world positions
    if (isrow) {
        int mypos = pos_of_phys[tid];
        float* dst = &Adump[mypos*172];
#pragma unroll
        for (int u4 = 0; u4 < 42; ++u4) {
            float4 v; v.x = row[4*u4]; v.y = row[4*u4+1]; v.z = row[4*u4+2]; v.w = row[4*u4+3];
            *reinterpret_cast<float4*>(&dst[4*u4]) = v;
        }
        dst[168] = row[168];
        dst[169] = 0.0f; dst[170] = 0.0f; dst[171] = 0.0f;
    }
    __syncthreads();
    // column unswap replay (reverse order)
    if (tid < PP) {
        for (int k = PP - 1; k >= 0; --k) {
            int q = perm_expl[k];
            if (q != k) {
                float t1 = Adump[tid*172 + k];
                Adump[tid*172 + k] = Adump[tid*172 + q];
                Adump[tid*172 + q] = t1;
            }
        }
    }
    __syncthreads();
    // prep2: Pinv -> frag layout (plain K), split hi/lo (full coverage, zero-fills padding)
    for (int o = tid; o < 6*2*11*512; o += 192) {
        int li = o & 511;
        int rest = o >> 9;
        int mt = rest % 11;
        int kp = rest / 11;
        int plane = kp & 1, ks = kp >> 1;
        int lane = li >> 3, j = li & 7;
        int rr = mt*16 + (lane & 15);
        int kc = ks*32 + 8*(lane>>4) + j;
        float val = (rr < PP && kc < PP) ? Adump[rr*172 + kc] : 0.0f;
        ushort h = f2bf(val);
        prep2[o] = plane ? f2bf(val - bf2f(h)) : h;
    }
}

// ---------------- fused: xr stage -> GEMM1 -> threshold -> t (LDS) -> GEMM2 -> fold (sharded) ----------------
__device__ __forceinline__ f32x4 mfma3(short8_t ah, short8_t al, short8_t bh, short8_t bl, f32x4 acc) {
    acc = __builtin_amdgcn_mfma_f32_16x16x32_bf16(ah, bh, acc, 0, 0, 0);
    acc = __builtin_amdgcn_mfma_f32_16x16x32_bf16(al, bh, acc, 0, 0, 0);
    acc = __builtin_amdgcn_mfma_f32_16x16x32_bf16(ah, bl, acc, 0, 0, 0);
    return acc;
}

// LDS: lds_t 12288 B | xr 2288 B | fp 2288 B  (total 16864)
__global__ __launch_bounds__(64, 3) void fused_kernel(
    const float* __restrict__ x,
    const ushort* __restrict__ prep1,
    const ushort* __restrict__ prep2,
    const float* __restrict__ sigma_,
    float* __restrict__ wmap,
    float* __restrict__ num)
{
    extern __shared__ char smem[];
    uint*  lds_t = (uint*)smem;                      // (rp*16+c)*2 dwords, uint2 per slot
    float* xr    = (float*)(smem + 12288);           // 13 x 44
    float* fp    = (float*)(smem + 12288 + 2288);    // 13 x 44

    int l = threadIdx.x;
    int q = l >> 4, c = l & 15;
    int n = blockIdx.z;
    int ho = blockIdx.y;
    int wo0 = blockIdx.x * 32;
    float lam = 6.0f * sigma_[0];
    const float* xn = x + n*HIMG*HIMG;
    const short8_t* p1v = reinterpret_cast<const short8_t*>(prep1);
    const short8_t* p2v = reinterpret_cast<const short8_t*>(prep2);

    // ---- stage xr (reflect-pad + affine fused) + init fp ----
    for (int idx = l; idx < 572; idx += 64) {
        int i = (idx*1490) >> 16;                    // idx/44
        int j = idx - i*44;
        int gi = ho + i - 12;
        gi = (gi < 0) ? -gi : gi; gi = (gi > HIMG-1) ? (2*(HIMG-1) - gi) : gi;
        int gj = wo0 + j - 12;
        gj = (gj < 0) ? -gj : gj; gj = (gj > HIMG-1) ? (2*(HIMG-1) - gj) : gj;
        xr[idx] = 2.0f * xn[gi*HIMG + gj] - 1.0f;
        fp[idx] = 0.0f;
    }
    __syncthreads();

    f32x4 acc[11][2];
#pragma unroll
    for (int mt = 0; mt < 11; ++mt)
#pragma unroll
      for (int cf = 0; cf < 2; ++cf) acc[mt][cf] = (f32x4){0.f,0.f,0.f,0.f};

    // ---- GEMM1: B built from LDS xr; A streamed from L2 ----
#pragma unroll 1
    for (int ks = 0; ks < 6; ++ks) {
        short8_t bh[2], bl[2];
#pragma unroll
        for (int cf = 0; cf < 2; ++cf) {
#pragma unroll
            for (int j = 0; j < 8; ++j) {
                int k = ks*32 + 8*q + j;
                float v = 0.0f;
                if (k < PP) {
                    int di = (k*5042) >> 16;          // k/13
                    int dj = k - 13*di;
                    v = xr[di*44 + cf*16 + c + dj];
                }
                ushort h = f2bf(v);
                bh[cf][j] = (short)h;
                bl[cf][j] = (short)f2bf(v - bf2f(h));
            }
        }
#pragma unroll
        for (int mt = 0; mt < 11; ++mt) {
            short8_t ah = p1v[((ks*2+0)*11 + mt)*64 + l];
            short8_t al = p1v[((ks*2+1)*11 + mt)*64 + l];
            acc[mt][0] = mfma3(ah, al, bh[0], bl[0], acc[mt][0]);
            acc[mt][1] = mfma3(ah, al, bh[1], bl[1], acc[mt][1]);
        }
    }

    // ---- per cf: threshold+count -> transpose t via LDS -> GEMM2 into same acc ----
    float wgts[2];
#pragma unroll
    for (int cf = 0; cf < 2; ++cf) {
        __syncthreads();   // lds_t free (prev cf's reads done)
        int cadd = 0;
#pragma unroll
        for (int mt = 0; mt < 11; ++mt) {
            uint ph[2], pl[2];
#pragma unroll
            for (int d = 0; d < 2; ++d) {
                ushort th2[2], tl2[2];
#pragma unroll
                for (int e2 = 0; e2 < 2; ++e2) {
                    int e = 2*d + e2;
                    int r = mt*16 + 4*q + e;
                    float dd = acc[mt][cf][e] / lam;
                    bool keep = fabsf(dd) > 1.0f;
                    float tv = keep ? dd*lam : 0.0f;
                    cadd += (keep && r > 0 && r < PP) ? 1 : 0;
                    th2[e2] = f2bf(tv);
                    tl2[e2] = f2bf(tv - bf2f(th2[e2]));
                }
                ph[d] = (uint)th2[0] | ((uint)th2[1] << 16);
                pl[d] = (uint)tl2[0] | ((uint)tl2[1] << 16);
            }
#pragma unroll
            for (int d = 0; d < 2; ++d) {
                int rp = mt*8 + q*2 + d;
                uint2 vv; vv.x = ph[d]; vv.y = pl[d];
                *reinterpret_cast<uint2*>(&lds_t[(rp*16 + c)*2]) = vv;
            }
        }
        // zero padding rows rp 88..95 (rows 176..191)
        {
            int rp = 88 + (l >> 3);
            int cc = (l & 7) * 2;
            uint2 z; z.x = 0u; z.y = 0u;
            *reinterpret_cast<uint2*>(&lds_t[(rp*16 + cc)*2]) = z;
            *reinterpret_cast<uint2*>(&lds_t[(rp*16 + cc + 1)*2]) = z;
        }
        cadd += __shfl_xor(cadd, 16);
        cadd += __shfl_xor(cadd, 32);
        int wo = wo0 + cf*16 + c;
        float wgt = (wo < HO) ? 1.0f/(1.0f + (float)cadd) : 0.0f;
        wgts[cf] = wgt;
        if (q == 0 && wo < HO) wmap[(n*HO + ho)*HO + wo] = wgt;
        __syncthreads();   // t visible
#pragma unroll
        for (int mt = 0; mt < 11; ++mt) acc[mt][cf] = (f32x4){0.f,0.f,0.f,0.f};
#pragma unroll 1
        for (int ks = 0; ks < 6; ++ks) {
            union { short8_t s; uint dd[4]; } BH, BL;
#pragma unroll
            for (int jp = 0; jp < 4; ++jp) {
                uint2 vv = *reinterpret_cast<const uint2*>(&lds_t[((ks*16 + 4*q + jp)*16 + c)*2]);
                BH.dd[jp] = vv.x; BL.dd[jp] = vv.y;
            }
#pragma unroll
            for (int mt = 0; mt < 11; ++mt) {
                short8_t ah = p2v[((ks*2+0)*11 + mt)*64 + l];
                short8_t al = p2v[((ks*2+1)*11 + mt)*64 + l];
                acc[mt][cf] = mfma3(ah, al, BH.s, BL.s, acc[mt][cf]);
            }
        }
    }

    // ---- fold into LDS footprint ----
    __syncthreads();
#pragma unroll
    for (int cf = 0; cf < 2; ++cf) {
#pragma unroll
        for (int mt = 0; mt < 11; ++mt) {
#pragma unroll
            for (int e = 0; e < 4; ++e) {
                int r = mt*16 + 4*q + e;
                if (r < PP) {
                    int di = (r*5042) >> 16;
                    int dj = r - 13*di;
                    atomicAdd(&fp[di*44 + cf*16 + c + dj], acc[mt][cf][e] * wgts[cf]);
                }
            }
        }
    }
    __syncthreads();
    // ---- commit to sharded num (atomics, 4x less same-address contention) ----
    float* nump = num + ((blockIdx.x + blockIdx.y) & (NSH-1))*(NIMG*HP*HP) + n*HP*HP;
    for (int idx = l; idx < 572; idx += 64) {
        int di = (idx*1490) >> 16;                  // idx/44
        int jj = idx - di*44;
        int gj = wo0 + jj;
        if (gj < HP) atomicAdd(&nump[(ho + di)*HP + gj], fp[idx]);
    }
}

// ---------------- final: out = (sum_shards num / box13(w) + 1)/2 ----------------
__global__ __launch_bounds__(256) void final_kernel(const float* __restrict__ num,
                                                    const float* __restrict__ wmap,
                                                    float* __restrict__ out)
{
    __shared__ float wr[28][28];
    int tid = threadIdx.x;
    int n = blockIdx.z;
    int y0 = blockIdx.y * 16, x0 = blockIdx.x * 16;
    const float* wp = wmap + n*HO*HO;
    for (int idx = tid; idx < 28*28; idx += 256) {
        int i = idx / 28, j = idx - (idx/28)*28;
        wr[i][j] = wp[(y0 + i)*HO + (x0 + j)];
    }
    __syncthreads();
    int py = tid >> 4, px = tid & 15;
    float dv = 0.0f;
#pragma unroll
    for (int a = 0; a < 13; ++a)
#pragma unroll
        for (int b = 0; b < 13; ++b)
            dv += wr[py + a][px + b];
    int y = y0 + py, x = x0 + px;
    int off = (n*HP + (y + 12))*HP + (x + 12);
    float nv = 0.0f;
#pragma unroll
    for (int s = 0; s < NSH; ++s) nv += num[s*(NIMG*HP*HP) + off];
    out[(n*HIMG + y)*HIMG + x] = (nv / dv + 1.0f) * 0.5f;
}

extern "C" void kernel_launch(void* const* d_in, const int* in_sizes, int n_in,
                              void* d_out, int out_size, void* d_ws, size_t ws_size,
                              hipStream_t stream) {
    const float* x      = (const float*)d_in[0];
    const float* sigma_ = (const float*)d_in[1];
    const float* Pm1    = (const float*)d_in[2];
    float* ws    = (float*)d_ws;
    float* wmap  = ws;                                // 287,296 f
    float* num   = ws + 287296;                       // 4 * 313,600 f
    ushort* prep1 = (ushort*)(ws + 287296 + 4*313600);   // 67,584 ushorts
    ushort* prep2 = (ushort*)(ws + 287296 + 4*313600 + 33792);
    float* out   = (float*)d_out;

    const int INV_LDS   = 29759 * 4;                  // 119,036 B
    const int FUSED_LDS = 12288 + 2288 + 2288;        // 16,864 B
    hipFuncSetAttribute((const void*)invert_kernel, hipFuncAttributeMaxDynamicSharedMemorySize, INV_LDS);

    hipMemsetAsync(num, 0, (size_t)NSH*NIMG*HP*HP*sizeof(float), stream);
    prep1_kernel<<<(6*11*512 + 255)/256, 256, 0, stream>>>(Pm1, prep1);
    invert_kernel<<<1, 192, INV_LDS, stream>>>(Pm1, prep2);
    dim3 grid((HO + 31)/32, HO, NIMG);                // 9 x 268 x 4, 64-thread blocks
    fused_kernel<<<grid, 64, FUSED_LDS, stream>>>(x, prep1, prep2, sigma_, wmap, num);
    dim3 gridD(HIMG/16, HIMG/16, NIMG);
    final_kernel<<<gridD, 256, 0, stream>>>(num, wmap, out);
}

// Round 9
// 780.108 us; speedup vs baseline: 4.3776x; 4.3776x over previous
//
#include <hip/hip_runtime.h>
#include <math.h>

#define P    13
#define PP   169
#define NIMG 4
#define HIMG 256
#define HP   280            // 256 + 2*12
#define HO   268            // 280 - 13 + 1

typedef __attribute__((ext_vector_type(8))) short short8_t;
typedef __attribute__((ext_vector_type(4))) float f32x4;

__device__ __forceinline__ ushort f2bf(float x) {
    union { float f; unsigned u; } a; a.f = x;
    unsigned r = a.u + 0x7fffu + ((a.u >> 16) & 1u);   // RNE
    return (ushort)(r >> 16);
}
__device__ __forceinline__ float bf2f(ushort b) {
    union { float f; unsigned u; } a; a.u = ((unsigned)b) << 16;
    return a.f;
}

// ---------------- prep1: Pm1 -> MFMA frag layout (plain K), split bf16 hi/lo (verified) ----------------
__global__ __launch_bounds__(256) void prep1_kernel(const float* __restrict__ Pm1,
                                                    ushort* __restrict__ prep1) {
    int idx = blockIdx.x*256 + threadIdx.x;
    if (idx >= 6*11*512) return;
    int j    = idx & 7;
    int lane = (idx >> 3) & 63;
    int rest = idx >> 9;
    int mt   = rest % 11;
    int ks   = rest / 11;
    int row  = mt*16 + (lane & 15);
    int k    = ks*32 + 8*(lane>>4) + j;
    float val = (row < PP && k < PP) ? Pm1[row*PP + k] : 0.0f;
    ushort h = f2bf(val);
    ushort lo = f2bf(val - bf2f(h));
    prep1[((ks*2+0)*11 + mt)*512 + lane*8 + j] = h;
    prep1[((ks*2+1)*11 + mt)*512 + lane*8 + j] = lo;
}

// ---------------- invert: register-blocked Gauss-Jordan (VERBATIM from verified R5 bench) ----------------
__global__ __launch_bounds__(512, 1) void invert_kernel(const float* __restrict__ Pm1,
                                                        ushort* __restrict__ prep2) {
    extern __shared__ float sm[];
    float* Adump = sm;                      // 169*192
    float* dcolB = sm + 169*192;            // 2*192
    float* prowB = dcolB + 384;             // 2*192
    float* krowB = prowB + 384;             // 2*192
    int*   perm  = (int*)(krowB + 384);     // 169

    int tid = threadIdx.x;
    int ti = tid >> 4, tj = tid & 15;
    int l64 = tid & 63;
    int row0 = 6*ti;

    float a[6][12];
#pragma unroll
    for (int m = 0; m < 6; ++m)
#pragma unroll
      for (int u = 0; u < 12; ++u) {
        int i = row0 + m, kc = 11*tj + u;
        a[m][u] = (i < PP && u < 11 && kc < PP) ? Pm1[i*PP + kc] : 0.0f;
      }
    __syncthreads();

    for (int k = 0; k < PP; ++k) {
        int par = k & 1;
        float* dcol = dcolB + par*192;
        float* prow = prowB + par*192;
        float* krow = krowB + par*192;
        int gk = (k*5958) >> 16;           // k/11
        int uk = k - 11*gk;
        if (tj == gk) {
#pragma unroll
            for (int u = 0; u < 12; ++u) if (u == uk) {
#pragma unroll
                for (int m = 0; m < 6; ++m) dcol[row0 + m] = a[m][u];
            }
        }
        __syncthreads();   // barrier A
        unsigned key = 0; float val = 0.0f;
        for (int i = k + l64; i < PP; i += 64) {
            float v = dcol[i];
            unsigned bits = __float_as_uint(fabsf(v));
            unsigned kk2 = (bits & 0xFFFFFF00u) | (unsigned)(255 - i);
            if (kk2 > key) { key = kk2; val = v; }
        }
#pragma unroll
        for (int m2 = 1; m2 < 64; m2 <<= 1) {
            unsigned ok = __shfl_xor(key, m2);
            float    ov = __shfl_xor(val, m2);
            if (ok > key) { key = ok; val = ov; }
        }
        int p = 255 - (int)(key & 0xFFu);
        float pv = val;
        int tip = (p*10923) >> 16;  int mp = p - 6*tip;   // p/6
        int tik = (k*10923) >> 16;  int mk = k - 6*tik;   // k/6
        if (ti == tip) {
#pragma unroll
            for (int m = 0; m < 6; ++m) if (m == mp) {
#pragma unroll
                for (int u4 = 0; u4 < 3; ++u4) {
                    float4 v4; v4.x=a[m][4*u4]; v4.y=a[m][4*u4+1]; v4.z=a[m][4*u4+2]; v4.w=a[m][4*u4+3];
                    *reinterpret_cast<float4*>(&prow[12*tj + 4*u4]) = v4;
                }
            }
        }
        if (ti == tik) {
#pragma unroll
            for (int m = 0; m < 6; ++m) if (m == mk) {
#pragma unroll
                for (int u4 = 0; u4 < 3; ++u4) {
                    float4 v4; v4.x=a[m][4*u4]; v4.y=a[m][4*u4+1]; v4.z=a[m][4*u4+2]; v4.w=a[m][4*u4+3];
                    *reinterpret_cast<float4*>(&krow[12*tj + 4*u4]) = v4;
                }
            }
        }
        if (tid == 0) perm[k] = p;
        __syncthreads();   // barrier B
        float invpv = 1.0f / pv;
        float s[12];
        {
            float4 p0 = *reinterpret_cast<float4*>(&prow[12*tj]);
            float4 p1 = *reinterpret_cast<float4*>(&prow[12*tj + 4]);
            float4 p2 = *reinterpret_cast<float4*>(&prow[12*tj + 8]);
            s[0]=p0.x*invpv; s[1]=p0.y*invpv; s[2]=p0.z*invpv; s[3]=p0.w*invpv;
            s[4]=p1.x*invpv; s[5]=p1.y*invpv; s[6]=p1.z*invpv; s[7]=p1.w*invpv;
            s[8]=p2.x*invpv; s[9]=p2.y*invpv; s[10]=p2.z*invpv; s[11]=p2.w*invpv;
        }
        bool myg = (tj == gk);
        if (myg) {
#pragma unroll
            for (int u = 0; u < 12; ++u) if (u == uk) {
                s[u] = invpv;
#pragma unroll
                for (int m = 0; m < 6; ++m) a[m][u] = 0.0f;
            }
        }
        float d[6];
#pragma unroll
        for (int m = 0; m < 6; ++m) d[m] = dcol[row0 + m];
#pragma unroll
        for (int m = 0; m < 6; ++m)
#pragma unroll
          for (int u = 0; u < 12; ++u)
            a[m][u] = __builtin_fmaf(-d[m], s[u], a[m][u]);
        if (ti == tik) {
#pragma unroll
            for (int m = 0; m < 6; ++m) if (m == mk) {
#pragma unroll
                for (int u = 0; u < 12; ++u) a[m][u] = s[u];
            }
        }
        if (p != k && ti == tip) {
            float dk = dcol[k];
            float kr[12];
            float4 k0 = *reinterpret_cast<float4*>(&krow[12*tj]);
            float4 k1 = *reinterpret_cast<float4*>(&krow[12*tj + 4]);
            float4 k2 = *reinterpret_cast<float4*>(&krow[12*tj + 8]);
            kr[0]=k0.x; kr[1]=k0.y; kr[2]=k0.z; kr[3]=k0.w;
            kr[4]=k1.x; kr[5]=k1.y; kr[6]=k1.z; kr[7]=k1.w;
            kr[8]=k2.x; kr[9]=k2.y; kr[10]=k2.z; kr[11]=k2.w;
            if (myg) {
#pragma unroll
                for (int u = 0; u < 12; ++u) if (u == uk) kr[u] = 0.0f;
            }
#pragma unroll
            for (int m = 0; m < 6; ++m) if (m == mp) {
#pragma unroll
                for (int u = 0; u < 12; ++u) a[m][u] = __builtin_fmaf(-dk, s[u], kr[u]);
            }
        }
    }
    __syncthreads();
#pragma unroll
    for (int m = 0; m < 6; ++m) {
        int i = row0 + m;
        if (i < PP) {
#pragma unroll
            for (int u4 = 0; u4 < 3; ++u4) {
                float4 v; v.x = a[m][4*u4]; v.y = a[m][4*u4+1]; v.z = a[m][4*u4+2]; v.w = a[m][4*u4+3];
                *reinterpret_cast<float4*>(&Adump[i*192 + 12*tj + 4*u4]) = v;
            }
        }
    }
    __syncthreads();
    if (tid < PP) {
        for (int k = PP - 1; k >= 0; --k) {
            int p = perm[k];
            if (p != k) {
                int gk2 = (k*5958)>>16, gp2 = (p*5958)>>16;
                int c1 = gk2*12 + (k - 11*gk2);
                int c2 = gp2*12 + (p - 11*gp2);
                float t1 = Adump[tid*192 + c1];
                Adump[tid*192 + c1] = Adump[tid*192 + c2];
                Adump[tid*192 + c2] = t1;
            }
        }
    }
    __syncthreads();
    for (int o = tid; o < 6*2*11*512; o += 512) {
        int li = o & 511;
        int rest = o >> 9;
        int mt = rest % 11;
        int kp = rest / 11;
        int plane = kp & 1, ks = kp >> 1;
        int lane = li >> 3, j = li & 7;
        int row = mt*16 + (lane & 15);
        int kk = ks*32 + 8*(lane>>4) + j;
        float val = 0.0f;
        if (row < PP && kk < PP) {
            int g = (kk*5958) >> 16;
            val = Adump[row*192 + g*12 + (kk - 11*g)];
        }
        ushort h = f2bf(val);
        prep2[o] = plane ? f2bf(val - bf2f(h)) : h;
    }
}

// ---------------- fused: 1-wave block, 16 cols, t transposed via __shfl (no LDS t) ----------------
__device__ __forceinline__ f32x4 mfma3(short8_t ah, short8_t al, short8_t bh, short8_t bl, f32x4 acc) {
    acc = __builtin_amdgcn_mfma_f32_16x16x32_bf16(ah, bh, acc, 0, 0, 0);
    acc = __builtin_amdgcn_mfma_f32_16x16x32_bf16(al, bh, acc, 0, 0, 0);
    acc = __builtin_amdgcn_mfma_f32_16x16x32_bf16(ah, bl, acc, 0, 0, 0);
    return acc;
}

__global__ __launch_bounds__(64, 2) void fused_kernel(
    const float* __restrict__ x,
    const ushort* __restrict__ prep1,
    const ushort* __restrict__ prep2,
    const float* __restrict__ sigma_,
    float* __restrict__ wmap,
    float* __restrict__ num)
{
    __shared__ float xr[13*28];     // staged x region (reflect-pad + affine)
    __shared__ float fp[13*28];     // fold footprint

    int l = threadIdx.x;
    int q = l >> 4, c = l & 15;
    int n = blockIdx.z;
    int ho = blockIdx.y;
    int wo0 = blockIdx.x * 16;
    float lam = 6.0f * sigma_[0];
    const float* xn = x + n*HIMG*HIMG;
    const short8_t* p1v = reinterpret_cast<const short8_t*>(prep1);
    const short8_t* p2v = reinterpret_cast<const short8_t*>(prep2);

    // ---- stage xr + zero fp ----
    for (int idx = l; idx < 364; idx += 64) {
        int i = (idx*2341) >> 16;                 // idx/28 (exact for idx<812)
        int j = idx - i*28;
        int gi = ho + i - 12;
        gi = (gi < 0) ? -gi : gi; gi = (gi > HIMG-1) ? (2*(HIMG-1) - gi) : gi;
        int gj = wo0 + j - 12;
        gj = (gj < 0) ? -gj : gj; gj = (gj > HIMG-1) ? (2*(HIMG-1) - gj) : gj;
        xr[idx] = 2.0f * xn[gi*HIMG + gj] - 1.0f;
        fp[idx] = 0.0f;
    }
    __syncthreads();

    // ---- GEMM1: B from xr, A1 streamed from L2 ----
    f32x4 acc[11];
#pragma unroll
    for (int mt = 0; mt < 11; ++mt) acc[mt] = (f32x4){0.f,0.f,0.f,0.f};
#pragma unroll 1
    for (int ks = 0; ks < 6; ++ks) {
        short8_t bh, bl;
#pragma unroll
        for (int j = 0; j < 8; ++j) {
            int k = ks*32 + 8*q + j;
            float v = 0.0f;
            if (k < PP) {
                int di = (k*5042) >> 16;          // k/13
                int dj = k - 13*di;
                v = xr[di*28 + c + dj];
            }
            ushort h = f2bf(v);
            bh[j] = (short)h;
            bl[j] = (short)f2bf(v - bf2f(h));
        }
#pragma unroll
        for (int mt = 0; mt < 11; ++mt) {
            short8_t ah = p1v[((ks*2+0)*11 + mt)*64 + l];
            short8_t al = p1v[((ks*2+1)*11 + mt)*64 + l];
            acc[mt] = mfma3(ah, al, bh, bl, acc[mt]);
        }
    }

    // ---- threshold + count + pack t into registers ----
    // lane (q,c): pk_*[mt][d] = bf16 pair of t rows {mt*16+4q+2d, +1} for col c
    int cadd = 0;
    uint pk_h[12][2], pk_l[12][2];
    pk_h[11][0] = 0u; pk_h[11][1] = 0u; pk_l[11][0] = 0u; pk_l[11][1] = 0u;
#pragma unroll
    for (int mt = 0; mt < 11; ++mt) {
#pragma unroll
        for (int d = 0; d < 2; ++d) {
            ushort th2[2], tl2[2];
#pragma unroll
            for (int e2 = 0; e2 < 2; ++e2) {
                int e = 2*d + e2;
                int r = mt*16 + 4*q + e;
                float dd = acc[mt][e] / lam;
                bool keep = fabsf(dd) > 1.0f;
                float tv = keep ? dd*lam : 0.0f;
                cadd += (keep && r > 0 && r < PP) ? 1 : 0;
                th2[e2] = f2bf(tv);
                tl2[e2] = f2bf(tv - bf2f(th2[e2]));
            }
            pk_h[mt][d] = (uint)th2[0] | ((uint)th2[1] << 16);
            pk_l[mt][d] = (uint)tl2[0] | ((uint)tl2[1] << 16);
        }
    }
    cadd += __shfl_xor(cadd, 16);
    cadd += __shfl_xor(cadd, 32);
    int wo = wo0 + c;
    float wgt = (wo < HO) ? 1.0f / (1.0f + (float)cadd) : 0.0f;
    if (q == 0 && wo < HO) wmap[(n*HO + ho)*HO + wo] = wgt;

    // ---- GEMM2: B assembled via shuffles from pk (full ks unroll; static pk indices) ----
    f32x4 rec[11];
#pragma unroll
    for (int mt = 0; mt < 11; ++mt) rec[mt] = (f32x4){0.f,0.f,0.f,0.f};
#pragma unroll
    for (int ks = 0; ks < 6; ++ks) {
        union { short8_t s; uint dd[4]; } BH, BL;
#pragma unroll
        for (int jp = 0; jp < 4; ++jp) {
            int s = ((2*q + (jp >> 1)) & 3)*16 + c;     // source lane
            uint ah0 = __shfl(pk_h[2*ks    ][jp & 1], s, 64);
            uint ah1 = __shfl(pk_h[2*ks + 1][jp & 1], s, 64);
            uint al0 = __shfl(pk_l[2*ks    ][jp & 1], s, 64);
            uint al1 = __shfl(pk_l[2*ks + 1][jp & 1], s, 64);
            BH.dd[jp] = (q >= 2) ? ah1 : ah0;
            BL.dd[jp] = (q >= 2) ? al1 : al0;
        }
#pragma unroll
        for (int mt = 0; mt < 11; ++mt) {
            short8_t ah = p2v[((ks*2+0)*11 + mt)*64 + l];
            short8_t al = p2v[((ks*2+1)*11 + mt)*64 + l];
            rec[mt] = mfma3(ah, al, BH.s, BL.s, rec[mt]);
        }
        __builtin_amdgcn_sched_barrier(0);   // keep A2 loads inside their ks iteration
    }

    // ---- fold into LDS footprint ----
#pragma unroll
    for (int mt = 0; mt < 11; ++mt) {
#pragma unroll
        for (int e = 0; e < 4; ++e) {
            int r = mt*16 + 4*q + e;
            if (r < PP) {
                int di = (r*5042) >> 16;              // r/13
                int dj = r - 13*di;
                atomicAdd(&fp[di*28 + c + dj], rec[mt][e] * wgt);
            }
        }
    }
    __syncthreads();

    // ---- flush: 364 global atomics per block ----
    float* nump = num + n*HP*HP;
    for (int idx = l; idx < 364; idx += 64) {
        int i = (idx*2341) >> 16;
        int j = idx - i*28;
        int gy = ho + i, gx = wo0 + j;
        if (gx < HP) atomicAdd(&nump[gy*HP + gx], fp[idx]);
    }
}

// ---------------- final: out = (num / box13(w) + 1)/2 (verified) ----------------
__global__ __launch_bounds__(256) void final_kernel(const float* __restrict__ num,
                                                    const float* __restrict__ wmap,
                                                    float* __restrict__ out)
{
    __shared__ float wr[28][28];
    int tid = threadIdx.x;
    int n = blockIdx.z;
    int y0 = blockIdx.y * 16, x0 = blockIdx.x * 16;
    const float* wp = wmap + n*HO*HO;
    for (int idx = tid; idx < 28*28; idx += 256) {
        int i = idx / 28, j = idx - (idx/28)*28;
        wr[i][j] = wp[(y0 + i)*HO + (x0 + j)];
    }
    __syncthreads();
    int py = tid >> 4, px = tid & 15;
    float dv = 0.0f;
#pragma unroll
    for (int a = 0; a < 13; ++a)
#pragma unroll
        for (int b = 0; b < 13; ++b)
            dv += wr[py + a][px + b];
    int y = y0 + py, x = x0 + px;
    float nv = num[(n*HP + (y + 12))*HP + (x + 12)];
    out[(n*HIMG + y)*HIMG + x] = (nv / dv + 1.0f) * 0.5f;
}

extern "C" void kernel_launch(void* const* d_in, const int* in_sizes, int n_in,
                              void* d_out, int out_size, void* d_ws, size_t ws_size,
                              hipStream_t stream) {
    const float* x      = (const float*)d_in[0];
    const float* sigma_ = (const float*)d_in[1];
    const float* Pm1    = (const float*)d_in[2];
    float* ws    = (float*)d_ws;
    float* wmap  = ws;                           // 287,296 f
    float* num   = ws + 287296;                  // 313,600 f
    ushort* prep1 = (ushort*)(ws + 600896);      // 67,584 ushorts
    ushort* prep2 = (ushort*)(ws + 634688);      // 67,584 ushorts
    float* out   = (float*)d_out;

    const int INV_LDS = (169*192 + 3*384)*4 + 169*4;   // 135,076
    hipFuncSetAttribute((const void*)invert_kernel, hipFuncAttributeMaxDynamicSharedMemorySize, INV_LDS);

    hipMemsetAsync(num, 0, (size_t)NIMG*HP*HP*sizeof(float), stream);
    prep1_kernel<<<(6*11*512 + 255)/256, 256, 0, stream>>>(Pm1, prep1);
    invert_kernel<<<1, 512, INV_LDS, stream>>>(Pm1, prep2);
    dim3 grid((HO + 15)/16, HO, NIMG);           // 17 x 268 x 4, 64-thread blocks
    fused_kernel<<<grid, 64, 0, stream>>>(x, prep1, prep2, sigma_, wmap, num);
    dim3 gridD(HIMG/16, HIMG/16, NIMG);
    final_kernel<<<gridD, 256, 0, stream>>>(num, wmap, out);
}

// Round 11
// 617.088 us; speedup vs baseline: 5.5340x; 1.2642x over previous
//
#include <hip/hip_runtime.h>
#include <math.h>

#define P    13
#define PP   169
#define NIMG 4
#define HIMG 256
#define HP   280            // 256 + 2*12
#define HO   268            // 280 - 13 + 1

typedef __attribute__((ext_vector_type(8))) short short8_t;
typedef __attribute__((ext_vector_type(4))) float f32x4;

__device__ __forceinline__ ushort f2bf(float x) {
    union { float f; unsigned u; } a; a.f = x;
    unsigned r = a.u + 0x7fffu + ((a.u >> 16) & 1u);   // RNE
    return (ushort)(r >> 16);
}
__device__ __forceinline__ float bf2f(ushort b) {
    union { float f; unsigned u; } a; a.u = ((unsigned)b) << 16;
    return a.f;
}

// ---------------- prep1: Pm1 -> MFMA frag layout (plain K), split bf16 hi/lo (verified) ----------------
__global__ __launch_bounds__(256) void prep1_kernel(const float* __restrict__ Pm1,
                                                    ushort* __restrict__ prep1) {
    int idx = blockIdx.x*256 + threadIdx.x;
    if (idx >= 6*11*512) return;
    int j    = idx & 7;
    int lane = (idx >> 3) & 63;
    int rest = idx >> 9;
    int mt   = rest % 11;
    int ks   = rest / 11;
    int row  = mt*16 + (lane & 15);
    int k    = ks*32 + 8*(lane>>4) + j;
    float val = (row < PP && k < PP) ? Pm1[row*PP + k] : 0.0f;
    ushort h = f2bf(val);
    ushort lo = f2bf(val - bf2f(h));
    prep1[((ks*2+0)*11 + mt)*512 + lane*8 + j] = h;
    prep1[((ks*2+1)*11 + mt)*512 + lane*8 + j] = lo;
}

// ---------------- invert: register-blocked Gauss-Jordan, NO pivoting, 1 barrier/iter ----------------
// 512 threads: ti=tid>>4 owns rows 6ti..6ti+5; tj=tid&15 owns cols 11tj..11tj+10.
// Per iter: owners publish col k + row k (pre-update), ONE barrier, rank-1 update with
// column-k fixup folded into the s-vector (supd[uk]=invpv+1 => col k becomes -d*invpv).
__global__ __launch_bounds__(512, 1) void invert_kernel(const float* __restrict__ Pm1,
                                                        ushort* __restrict__ prep2) {
    extern __shared__ float sm[];
    float* Adump = sm;                      // 169*192 = 32448
    float* dcolB = sm + 32448;              // 2*192
    float* prowB = dcolB + 384;             // 2*192

    int tid = threadIdx.x;
    int ti = tid >> 4, tj = tid & 15;
    int row0 = 6*ti;

    float a[6][12];
#pragma unroll
    for (int m = 0; m < 6; ++m)
#pragma unroll
      for (int u = 0; u < 12; ++u) {
        int i = row0 + m, kc = 11*tj + u;
        a[m][u] = (i < PP && u < 11 && kc < PP) ? Pm1[i*PP + kc] : 0.0f;
      }
    __syncthreads();

    for (int k = 0; k < PP; ++k) {
        int par = k & 1;
        float* dcol = dcolB + par*192;
        float* prow = prowB + par*192;
        int gk = (k*5958) >> 16;            // k/11
        int uk = k - 11*gk;
        int tik = (k*10923) >> 16;          // k/6
        int mk = k - 6*tik;

        // publish column k (owner col-group; value selected by cndmask chain)
        if (tj == gk) {
#pragma unroll
            for (int m = 0; m < 6; ++m) {
                float v = a[m][0];
#pragma unroll
                for (int u = 1; u < 12; ++u) v = (u == uk) ? a[m][u] : v;
                dcol[row0 + m] = v;
            }
        }
        // publish row k (owner row-group; wave-skippable in 7/8 waves)
        if (ti == tik) {
#pragma unroll
            for (int m = 0; m < 6; ++m) if (m == mk) {
#pragma unroll
                for (int u4 = 0; u4 < 3; ++u4) {
                    float4 v4; v4.x=a[m][4*u4]; v4.y=a[m][4*u4+1]; v4.z=a[m][4*u4+2]; v4.w=a[m][4*u4+3];
                    *reinterpret_cast<float4*>(&prow[12*tj + 4*u4]) = v4;
                }
            }
        }
        __syncthreads();   // the ONE barrier

        float pv = dcol[k];
        float invpv = 1.0f / pv;
        float4 p0 = *reinterpret_cast<float4*>(&prow[12*tj]);
        float4 p1 = *reinterpret_cast<float4*>(&prow[12*tj + 4]);
        float4 p2 = *reinterpret_cast<float4*>(&prow[12*tj + 8]);
        float pr[12] = {p0.x,p0.y,p0.z,p0.w, p1.x,p1.y,p1.z,p1.w, p2.x,p2.y,p2.z,p2.w};
        bool myg = (tj == gk);
        float strue[12], supd[12];
#pragma unroll
        for (int u = 0; u < 12; ++u) {
            bool isuk = myg && (u == uk);
            float sv = pr[u] * invpv;
            strue[u] = isuk ? invpv : sv;
            supd[u]  = isuk ? (invpv + 1.0f) : sv;
        }
        float d[6];
#pragma unroll
        for (int m = 0; m < 6; ++m) d[m] = dcol[row0 + m];
        // rank-1 update; col uk automatically becomes -d*invpv via supd
#pragma unroll
        for (int m = 0; m < 6; ++m)
#pragma unroll
          for (int u = 0; u < 12; ++u)
            a[m][u] = __builtin_fmaf(-d[m], supd[u], a[m][u]);
        // row k overwrite: scaled pivot row (wave-skippable in 7/8 waves)
        if (ti == tik) {
#pragma unroll
            for (int m = 0; m < 6; ++m) if (m == mk) {
#pragma unroll
                for (int u = 0; u < 12; ++u) a[m][u] = strue[u];
            }
        }
    }
    __syncthreads();

    // dump to LDS (no permutation to undo)
#pragma unroll
    for (int m = 0; m < 6; ++m) {
        int i = row0 + m;
        if (i < PP) {
#pragma unroll
            for (int u4 = 0; u4 < 3; ++u4) {
                float4 v; v.x = a[m][4*u4]; v.y = a[m][4*u4+1]; v.z = a[m][4*u4+2]; v.w = a[m][4*u4+3];
                *reinterpret_cast<float4*>(&Adump[i*192 + 12*tj + 4*u4]) = v;
            }
        }
    }
    __syncthreads();
    // prep2: Pinv -> frag layout (plain K), split hi/lo
    for (int o = tid; o < 6*2*11*512; o += 512) {
        int li = o & 511;
        int rest = o >> 9;
        int mt = rest % 11;
        int kp = rest / 11;
        int plane = kp & 1, ks = kp >> 1;
        int lane = li >> 3, j = li & 7;
        int row = mt*16 + (lane & 15);
        int kk = ks*32 + 8*(lane>>4) + j;
        float val = 0.0f;
        if (row < PP && kk < PP) {
            int g = (kk*5958) >> 16;
            val = Adump[row*192 + g*12 + (kk - 11*g)];
        }
        ushort h = f2bf(val);
        prep2[o] = plane ? f2bf(val - bf2f(h)) : h;
    }
}

// ---------------- fused: 1-wave block, 16 cols, t via __shfl (VERBATIM from verified R9) ----------------
__device__ __forceinline__ f32x4 mfma3(short8_t ah, short8_t al, short8_t bh, short8_t bl, f32x4 acc) {
    acc = __builtin_amdgcn_mfma_f32_16x16x32_bf16(ah, bh, acc, 0, 0, 0);
    acc = __builtin_amdgcn_mfma_f32_16x16x32_bf16(al, bh, acc, 0, 0, 0);
    acc = __builtin_amdgcn_mfma_f32_16x16x32_bf16(ah, bl, acc, 0, 0, 0);
    return acc;
}

__global__ __launch_bounds__(64, 2) void fused_kernel(
    const float* __restrict__ x,
    const ushort* __restrict__ prep1,
    const ushort* __restrict__ prep2,
    const float* __restrict__ sigma_,
    float* __restrict__ wmap,
    float* __restrict__ num)
{
    __shared__ float xr[13*28];     // staged x region (reflect-pad + affine)
    __shared__ float fp[13*28];     // fold footprint

    int l = threadIdx.x;
    int q = l >> 4, c = l & 15;
    int n = blockIdx.z;
    int ho = blockIdx.y;
    int wo0 = blockIdx.x * 16;
    float lam = 6.0f * sigma_[0];
    const float* xn = x + n*HIMG*HIMG;
    const short8_t* p1v = reinterpret_cast<const short8_t*>(prep1);
    const short8_t* p2v = reinterpret_cast<const short8_t*>(prep2);

    // ---- stage xr + zero fp ----
    for (int idx = l; idx < 364; idx += 64) {
        int i = (idx*2341) >> 16;                 // idx/28 (exact for idx<812)
        int j = idx - i*28;
        int gi = ho + i - 12;
        gi = (gi < 0) ? -gi : gi; gi = (gi > HIMG-1) ? (2*(HIMG-1) - gi) : gi;
        int gj = wo0 + j - 12;
        gj = (gj < 0) ? -gj : gj; gj = (gj > HIMG-1) ? (2*(HIMG-1) - gj) : gj;
        xr[idx] = 2.0f * xn[gi*HIMG + gj] - 1.0f;
        fp[idx] = 0.0f;
    }
    __syncthreads();

    // ---- GEMM1: B from xr, A1 streamed from L2 ----
    f32x4 acc[11];
#pragma unroll
    for (int mt = 0; mt < 11; ++mt) acc[mt] = (f32x4){0.f,0.f,0.f,0.f};
#pragma unroll 1
    for (int ks = 0; ks < 6; ++ks) {
        short8_t bh, bl;
#pragma unroll
        for (int j = 0; j < 8; ++j) {
            int k = ks*32 + 8*q + j;
            float v = 0.0f;
            if (k < PP) {
                int di = (k*5042) >> 16;          // k/13
                int dj = k - 13*di;
                v = xr[di*28 + c + dj];
            }
            ushort h = f2bf(v);
            bh[j] = (short)h;
            bl[j] = (short)f2bf(v - bf2f(h));
        }
#pragma unroll
        for (int mt = 0; mt < 11; ++mt) {
            short8_t ah = p1v[((ks*2+0)*11 + mt)*64 + l];
            short8_t al = p1v[((ks*2+1)*11 + mt)*64 + l];
            acc[mt] = mfma3(ah, al, bh, bl, acc[mt]);
        }
    }

    // ---- threshold + count + pack t into registers ----
    int cadd = 0;
    uint pk_h[12][2], pk_l[12][2];
    pk_h[11][0] = 0u; pk_h[11][1] = 0u; pk_l[11][0] = 0u; pk_l[11][1] = 0u;
#pragma unroll
    for (int mt = 0; mt < 11; ++mt) {
#pragma unroll
        for (int d = 0; d < 2; ++d) {
            ushort th2[2], tl2[2];
#pragma unroll
            for (int e2 = 0; e2 < 2; ++e2) {
                int e = 2*d + e2;
                int r = mt*16 + 4*q + e;
                float dd = acc[mt][e] / lam;
                bool keep = fabsf(dd) > 1.0f;
                float tv = keep ? dd*lam : 0.0f;
                cadd += (keep && r > 0 && r < PP) ? 1 : 0;
                th2[e2] = f2bf(tv);
                tl2[e2] = f2bf(tv - bf2f(th2[e2]));
            }
            pk_h[mt][d] = (uint)th2[0] | ((uint)th2[1] << 16);
            pk_l[mt][d] = (uint)tl2[0] | ((uint)tl2[1] << 16);
        }
    }
    cadd += __shfl_xor(cadd, 16);
    cadd += __shfl_xor(cadd, 32);
    int wo = wo0 + c;
    float wgt = (wo < HO) ? 1.0f / (1.0f + (float)cadd) : 0.0f;
    if (q == 0 && wo < HO) wmap[(n*HO + ho)*HO + wo] = wgt;

    // ---- GEMM2: B assembled via shuffles from pk (full ks unroll; static pk indices) ----
    f32x4 rec[11];
#pragma unroll
    for (int mt = 0; mt < 11; ++mt) rec[mt] = (f32x4){0.f,0.f,0.f,0.f};
#pragma unroll
    for (int ks = 0; ks < 6; ++ks) {
        union { short8_t s; uint dd[4]; } BH, BL;
#pragma unroll
        for (int jp = 0; jp < 4; ++jp) {
            int s = ((2*q + (jp >> 1)) & 3)*16 + c;     // source lane
            uint ah0 = __shfl(pk_h[2*ks    ][jp & 1], s, 64);
            uint ah1 = __shfl(pk_h[2*ks + 1][jp & 1], s, 64);
            uint al0 = __shfl(pk_l[2*ks    ][jp & 1], s, 64);
            uint al1 = __shfl(pk_l[2*ks + 1][jp & 1], s, 64);
            BH.dd[jp] = (q >= 2) ? ah1 : ah0;
            BL.dd[jp] = (q >= 2) ? al1 : al0;
        }
#pragma unroll
        for (int mt = 0; mt < 11; ++mt) {
            short8_t ah = p2v[((ks*2+0)*11 + mt)*64 + l];
            short8_t al = p2v[((ks*2+1)*11 + mt)*64 + l];
            rec[mt] = mfma3(ah, al, BH.s, BL.s, rec[mt]);
        }
        __builtin_amdgcn_sched_barrier(0);   // keep A2 loads inside their ks iteration
    }

    // ---- fold into LDS footprint ----
#pragma unroll
    for (int mt = 0; mt < 11; ++mt) {
#pragma unroll
        for (int e = 0; e < 4; ++e) {
            int r = mt*16 + 4*q + e;
            if (r < PP) {
                int di = (r*5042) >> 16;              // r/13
                int dj = r - 13*di;
                atomicAdd(&fp[di*28 + c + dj], rec[mt][e] * wgt);
            }
        }
    }
    __syncthreads();

    // ---- flush: 364 global atomics per block ----
    float* nump = num + n*HP*HP;
    for (int idx = l; idx < 364; idx += 64) {
        int i = (idx*2341) >> 16;
        int j = idx - i*28;
        int gy = ho + i, gx = wo0 + j;
        if (gx < HP) atomicAdd(&nump[gy*HP + gx], fp[idx]);
    }
}

// ---------------- final: out = (num / box13(w) + 1)/2 (verified) ----------------
__global__ __launch_bounds__(256) void final_kernel(const float* __restrict__ num,
                                                    const float* __restrict__ wmap,
                                                    float* __restrict__ out)
{
    __shared__ float wr[28][28];
    int tid = threadIdx.x;
    int n = blockIdx.z;
    int y0 = blockIdx.y * 16, x0 = blockIdx.x * 16;
    const float* wp = wmap + n*HO*HO;
    for (int idx = tid; idx < 28*28; idx += 256) {
        int i = idx / 28, j = idx - (idx/28)*28;
        wr[i][j] = wp[(y0 + i)*HO + (x0 + j)];
    }
    __syncthreads();
    int py = tid >> 4, px = tid & 15;
    float dv = 0.0f;
#pragma unroll
    for (int a = 0; a < 13; ++a)
#pragma unroll
        for (int b = 0; b < 13; ++b)
            dv += wr[py + a][px + b];
    int y = y0 + py, x = x0 + px;
    float nv = num[(n*HP + (y + 12))*HP + (x + 12)];
    out[(n*HIMG + y)*HIMG + x] = (nv / dv + 1.0f) * 0.5f;
}

extern "C" void kernel_launch(void* const* d_in, const int* in_sizes, int n_in,
                              void* d_out, int out_size, void* d_ws, size_t ws_size,
                              hipStream_t stream) {
    const float* x      = (const float*)d_in[0];
    const float* sigma_ = (const float*)d_in[1];
    const float* Pm1    = (const float*)d_in[2];
    float* ws    = (float*)d_ws;
    float* wmap  = ws;                           // 287,296 f
    float* num   = ws + 287296;                  // 313,600 f
    ushort* prep1 = (ushort*)(ws + 600896);      // 67,584 ushorts
    ushort* prep2 = (ushort*)(ws + 634688);      // 67,584 ushorts
    float* out   = (float*)d_out;

    const int INV_LDS = (32448 + 2*384) * 4;     // 132,864 B
    hipFuncSetAttribute((const void*)invert_kernel, hipFuncAttributeMaxDynamicSharedMemorySize, INV_LDS);

    hipMemsetAsync(num, 0, (size_t)NIMG*HP*HP*sizeof(float), stream);
    prep1_kernel<<<(6*11*512 + 255)/256, 256, 0, stream>>>(Pm1, prep1);
    invert_kernel<<<1, 512, INV_LDS, stream>>>(Pm1, prep2);
    dim3 grid((HO + 15)/16, HO, NIMG);           // 17 x 268 x 4, 64-thread blocks
    fused_kernel<<<grid, 64, 0, stream>>>(x, prep1, prep2, sigma_, wmap, num);
    dim3 gridD(HIMG/16, HIMG/16, NIMG);
    final_kernel<<<gridD, 256, 0, stream>>>(num, wmap, out);
}

// Round 12
// 604.714 us; speedup vs baseline: 5.6473x; 1.0205x over previous
//
#include <hip/hip_runtime.h>
#include <math.h>

#define P    13
#define PP   169
#define NIMG 4
#define HIMG 256
#define HP   280            // 256 + 2*12
#define HO   268            // 280 - 13 + 1

typedef __attribute__((ext_vector_type(8))) short short8_t;
typedef __attribute__((ext_vector_type(4))) float f32x4;

__device__ __forceinline__ ushort f2bf(float x) {
    union { float f; unsigned u; } a; a.f = x;
    unsigned r = a.u + 0x7fffu + ((a.u >> 16) & 1u);   // RNE
    return (ushort)(r >> 16);
}
__device__ __forceinline__ float bf2f(ushort b) {
    union { float f; unsigned u; } a; a.u = ((unsigned)b) << 16;
    return a.f;
}

// ---------------- prep1: Pm1 -> MFMA frag layout (plain K), split bf16 hi/lo (verified) ----------------
__global__ __launch_bounds__(256) void prep1_kernel(const float* __restrict__ Pm1,
                                                    ushort* __restrict__ prep1) {
    int idx = blockIdx.x*256 + threadIdx.x;
    if (idx >= 6*11*512) return;
    int j    = idx & 7;
    int lane = (idx >> 3) & 63;
    int rest = idx >> 9;
    int mt   = rest % 11;
    int ks   = rest / 11;
    int row  = mt*16 + (lane & 15);
    int k    = ks*32 + 8*(lane>>4) + j;
    float val = (row < PP && k < PP) ? Pm1[row*PP + k] : 0.0f;
    ushort h = f2bf(val);
    ushort lo = f2bf(val - bf2f(h));
    prep1[((ks*2+0)*11 + mt)*512 + lane*8 + j] = h;
    prep1[((ks*2+1)*11 + mt)*512 + lane*8 + j] = lo;
}

// ---------------- invert: no-pivot register-blocked Gauss-Jordan (VERBATIM verified R11) ----------------
__global__ __launch_bounds__(512, 1) void invert_kernel(const float* __restrict__ Pm1,
                                                        ushort* __restrict__ prep2) {
    extern __shared__ float sm[];
    float* Adump = sm;                      // 169*192 = 32448
    float* dcolB = sm + 32448;              // 2*192
    float* prowB = dcolB + 384;             // 2*192

    int tid = threadIdx.x;
    int ti = tid >> 4, tj = tid & 15;
    int row0 = 6*ti;

    float a[6][12];
#pragma unroll
    for (int m = 0; m < 6; ++m)
#pragma unroll
      for (int u = 0; u < 12; ++u) {
        int i = row0 + m, kc = 11*tj + u;
        a[m][u] = (i < PP && u < 11 && kc < PP) ? Pm1[i*PP + kc] : 0.0f;
      }
    __syncthreads();

    for (int k = 0; k < PP; ++k) {
        int par = k & 1;
        float* dcol = dcolB + par*192;
        float* prow = prowB + par*192;
        int gk = (k*5958) >> 16;            // k/11
        int uk = k - 11*gk;
        int tik = (k*10923) >> 16;          // k/6
        int mk = k - 6*tik;

        if (tj == gk) {
#pragma unroll
            for (int m = 0; m < 6; ++m) {
                float v = a[m][0];
#pragma unroll
                for (int u = 1; u < 12; ++u) v = (u == uk) ? a[m][u] : v;
                dcol[row0 + m] = v;
            }
        }
        if (ti == tik) {
#pragma unroll
            for (int m = 0; m < 6; ++m) if (m == mk) {
#pragma unroll
                for (int u4 = 0; u4 < 3; ++u4) {
                    float4 v4; v4.x=a[m][4*u4]; v4.y=a[m][4*u4+1]; v4.z=a[m][4*u4+2]; v4.w=a[m][4*u4+3];
                    *reinterpret_cast<float4*>(&prow[12*tj + 4*u4]) = v4;
                }
            }
        }
        __syncthreads();   // the ONE barrier

        float pv = dcol[k];
        float invpv = 1.0f / pv;
        float4 p0 = *reinterpret_cast<float4*>(&prow[12*tj]);
        float4 p1 = *reinterpret_cast<float4*>(&prow[12*tj + 4]);
        float4 p2 = *reinterpret_cast<float4*>(&prow[12*tj + 8]);
        float pr[12] = {p0.x,p0.y,p0.z,p0.w, p1.x,p1.y,p1.z,p1.w, p2.x,p2.y,p2.z,p2.w};
        bool myg = (tj == gk);
        float strue[12], supd[12];
#pragma unroll
        for (int u = 0; u < 12; ++u) {
            bool isuk = myg && (u == uk);
            float sv = pr[u] * invpv;
            strue[u] = isuk ? invpv : sv;
            supd[u]  = isuk ? (invpv + 1.0f) : sv;
        }
        float d[6];
#pragma unroll
        for (int m = 0; m < 6; ++m) d[m] = dcol[row0 + m];
#pragma unroll
        for (int m = 0; m < 6; ++m)
#pragma unroll
          for (int u = 0; u < 12; ++u)
            a[m][u] = __builtin_fmaf(-d[m], supd[u], a[m][u]);
        if (ti == tik) {
#pragma unroll
            for (int m = 0; m < 6; ++m) if (m == mk) {
#pragma unroll
                for (int u = 0; u < 12; ++u) a[m][u] = strue[u];
            }
        }
    }
    __syncthreads();

#pragma unroll
    for (int m = 0; m < 6; ++m) {
        int i = row0 + m;
        if (i < PP) {
#pragma unroll
            for (int u4 = 0; u4 < 3; ++u4) {
                float4 v; v.x = a[m][4*u4]; v.y = a[m][4*u4+1]; v.z = a[m][4*u4+2]; v.w = a[m][4*u4+3];
                *reinterpret_cast<float4*>(&Adump[i*192 + 12*tj + 4*u4]) = v;
            }
        }
    }
    __syncthreads();
    for (int o = tid; o < 6*2*11*512; o += 512) {
        int li = o & 511;
        int rest = o >> 9;
        int mt = rest % 11;
        int kp = rest / 11;
        int plane = kp & 1, ks = kp >> 1;
        int lane = li >> 3, j = li & 7;
        int row = mt*16 + (lane & 15);
        int kk = ks*32 + 8*(lane>>4) + j;
        float val = 0.0f;
        if (row < PP && kk < PP) {
            int g = (kk*5958) >> 16;
            val = Adump[row*192 + g*12 + (kk - 11*g)];
        }
        ushort h = f2bf(val);
        prep2[o] = plane ? f2bf(val - bf2f(h)) : h;
    }
}

// ---------------- fused: R11 structure; scheduler un-handcuffed, occupancy pinned ----------------
__device__ __forceinline__ f32x4 mfma3(short8_t ah, short8_t al, short8_t bh, short8_t bl, f32x4 acc) {
    acc = __builtin_amdgcn_mfma_f32_16x16x32_bf16(ah, bh, acc, 0, 0, 0);
    acc = __builtin_amdgcn_mfma_f32_16x16x32_bf16(al, bh, acc, 0, 0, 0);
    acc = __builtin_amdgcn_mfma_f32_16x16x32_bf16(ah, bl, acc, 0, 0, 0);
    return acc;
}

__global__ __launch_bounds__(64, 3) void fused_kernel(
    const float* __restrict__ x,
    const ushort* __restrict__ prep1,
    const ushort* __restrict__ prep2,
    const float* __restrict__ sigma_,
    float* __restrict__ wmap,
    float* __restrict__ num)
{
    __shared__ float xr[13*28];     // staged x region (reflect-pad + affine)
    __shared__ float fp[13*28];     // fold footprint

    int l = threadIdx.x;
    int q = l >> 4, c = l & 15;
    int n = blockIdx.z;
    int ho = blockIdx.y;
    int wo0 = blockIdx.x * 16;
    float lam = 6.0f * sigma_[0];
    const float* xn = x + n*HIMG*HIMG;
    const short8_t* p1v = reinterpret_cast<const short8_t*>(prep1);
    const short8_t* p2v = reinterpret_cast<const short8_t*>(prep2);

    // ---- stage xr + zero fp ----
    for (int idx = l; idx < 364; idx += 64) {
        int i = (idx*2341) >> 16;                 // idx/28 (exact for idx<812)
        int j = idx - i*28;
        int gi = ho + i - 12;
        gi = (gi < 0) ? -gi : gi; gi = (gi > HIMG-1) ? (2*(HIMG-1) - gi) : gi;
        int gj = wo0 + j - 12;
        gj = (gj < 0) ? -gj : gj; gj = (gj > HIMG-1) ? (2*(HIMG-1) - gj) : gj;
        xr[idx] = 2.0f * xn[gi*HIMG + gj] - 1.0f;
        fp[idx] = 0.0f;
    }
    __syncthreads();

    // ---- GEMM1: B from xr, A1 streamed from L2 (compiler-pipelined across ks) ----
    f32x4 acc[11];
#pragma unroll
    for (int mt = 0; mt < 11; ++mt) acc[mt] = (f32x4){0.f,0.f,0.f,0.f};
#pragma unroll 2
    for (int ks = 0; ks < 6; ++ks) {
        short8_t bh, bl;
#pragma unroll
        for (int j = 0; j < 8; ++j) {
            int k = ks*32 + 8*q + j;
            float v = 0.0f;
            if (k < PP) {
                int di = (k*5042) >> 16;          // k/13
                int dj = k - 13*di;
                v = xr[di*28 + c + dj];
            }
            ushort h = f2bf(v);
            bh[j] = (short)h;
            bl[j] = (short)f2bf(v - bf2f(h));
        }
#pragma unroll
        for (int mt = 0; mt < 11; ++mt) {
            short8_t ah = p1v[((ks*2+0)*11 + mt)*64 + l];
            short8_t al = p1v[((ks*2+1)*11 + mt)*64 + l];
            acc[mt] = mfma3(ah, al, bh, bl, acc[mt]);
        }
    }

    // ---- threshold + count + pack t into registers ----
    int cadd = 0;
    uint pk_h[12][2], pk_l[12][2];
    pk_h[11][0] = 0u; pk_h[11][1] = 0u; pk_l[11][0] = 0u; pk_l[11][1] = 0u;
#pragma unroll
    for (int mt = 0; mt < 11; ++mt) {
#pragma unroll
        for (int d = 0; d < 2; ++d) {
            ushort th2[2], tl2[2];
#pragma unroll
            for (int e2 = 0; e2 < 2; ++e2) {
                int e = 2*d + e2;
                int r = mt*16 + 4*q + e;
                float dd = acc[mt][e] / lam;
                bool keep = fabsf(dd) > 1.0f;
                float tv = keep ? dd*lam : 0.0f;
                cadd += (keep && r > 0 && r < PP) ? 1 : 0;
                th2[e2] = f2bf(tv);
                tl2[e2] = f2bf(tv - bf2f(th2[e2]));
            }
            pk_h[mt][d] = (uint)th2[0] | ((uint)th2[1] << 16);
            pk_l[mt][d] = (uint)tl2[0] | ((uint)tl2[1] << 16);
        }
    }
    cadd += __shfl_xor(cadd, 16);
    cadd += __shfl_xor(cadd, 32);
    int wo = wo0 + c;
    float wgt = (wo < HO) ? 1.0f / (1.0f + (float)cadd) : 0.0f;
    if (q == 0 && wo < HO) wmap[(n*HO + ho)*HO + wo] = wgt;

    // ---- GEMM2: B via shuffles from pk (full unroll; NO sched_barrier — let scheduler overlap) ----
    f32x4 rec[11];
#pragma unroll
    for (int mt = 0; mt < 11; ++mt) rec[mt] = (f32x4){0.f,0.f,0.f,0.f};
#pragma unroll
    for (int ks = 0; ks < 6; ++ks) {
        union { short8_t s; uint dd[4]; } BH, BL;
#pragma unroll
        for (int jp = 0; jp < 4; ++jp) {
            int s = ((2*q + (jp >> 1)) & 3)*16 + c;     // source lane
            uint ah0 = __shfl(pk_h[2*ks    ][jp & 1], s, 64);
            uint ah1 = __shfl(pk_h[2*ks + 1][jp & 1], s, 64);
            uint al0 = __shfl(pk_l[2*ks    ][jp & 1], s, 64);
            uint al1 = __shfl(pk_l[2*ks + 1][jp & 1], s, 64);
            BH.dd[jp] = (q >= 2) ? ah1 : ah0;
            BL.dd[jp] = (q >= 2) ? al1 : al0;
        }
#pragma unroll
        for (int mt = 0; mt < 11; ++mt) {
            short8_t ah = p2v[((ks*2+0)*11 + mt)*64 + l];
            short8_t al = p2v[((ks*2+1)*11 + mt)*64 + l];
            rec[mt] = mfma3(ah, al, BH.s, BL.s, rec[mt]);
        }
    }

    // ---- fold into LDS footprint ----
#pragma unroll
    for (int mt = 0; mt < 11; ++mt) {
#pragma unroll
        for (int e = 0; e < 4; ++e) {
            int r = mt*16 + 4*q + e;
            if (r < PP) {
                int di = (r*5042) >> 16;              // r/13
                int dj = r - 13*di;
                atomicAdd(&fp[di*28 + c + dj], rec[mt][e] * wgt);
            }
        }
    }
    __syncthreads();

    // ---- flush: 364 global atomics per block ----
    float* nump = num + n*HP*HP;
    for (int idx = l; idx < 364; idx += 64) {
        int i = (idx*2341) >> 16;
        int j = idx - i*28;
        int gy = ho + i, gx = wo0 + j;
        if (gx < HP) atomicAdd(&nump[gy*HP + gx], fp[idx]);
    }
}

// ---------------- final: out = (num / box13(w) + 1)/2 (verified) ----------------
__global__ __launch_bounds__(256) void final_kernel(const float* __restrict__ num,
                                                    const float* __restrict__ wmap,
                                                    float* __restrict__ out)
{
    __shared__ float wr[28][28];
    int tid = threadIdx.x;
    int n = blockIdx.z;
    int y0 = blockIdx.y * 16, x0 = blockIdx.x * 16;
    const float* wp = wmap + n*HO*HO;
    for (int idx = tid; idx < 28*28; idx += 256) {
        int i = idx / 28, j = idx - (idx/28)*28;
        wr[i][j] = wp[(y0 + i)*HO + (x0 + j)];
    }
    __syncthreads();
    int py = tid >> 4, px = tid & 15;
    float dv = 0.0f;
#pragma unroll
    for (int a = 0; a < 13; ++a)
#pragma unroll
        for (int b = 0; b < 13; ++b)
            dv += wr[py + a][px + b];
    int y = y0 + py, x = x0 + px;
    float nv = num[(n*HP + (y + 12))*HP + (x + 12)];
    out[(n*HIMG + y)*HIMG + x] = (nv / dv + 1.0f) * 0.5f;
}

extern "C" void kernel_launch(void* const* d_in, const int* in_sizes, int n_in,
                              void* d_out, int out_size, void* d_ws, size_t ws_size,
                              hipStream_t stream) {
    const float* x      = (const float*)d_in[0];
    const float* sigma_ = (const float*)d_in[1];
    const float* Pm1    = (const float*)d_in[2];
    float* ws    = (float*)d_ws;
    float* wmap  = ws;                           // 287,296 f
    float* num   = ws + 287296;                  // 313,600 f
    ushort* prep1 = (ushort*)(ws + 600896);      // 67,584 ushorts
    ushort* prep2 = (ushort*)(ws + 634688);      // 67,584 ushorts
    float* out   = (float*)d_out;

    const int INV_LDS = (32448 + 2*384) * 4;     // 132,864 B
    hipFuncSetAttribute((const void*)invert_kernel, hipFuncAttributeMaxDynamicSharedMemorySize, INV_LDS);

    hipMemsetAsync(num, 0, (size_t)NIMG*HP*HP*sizeof(float), stream);
    prep1_kernel<<<(6*11*512 + 255)/256, 256, 0, stream>>>(Pm1, prep1);
    invert_kernel<<<1, 512, INV_LDS, stream>>>(Pm1, prep2);
    dim3 grid((HO + 15)/16, HO, NIMG);           // 17 x 268 x 4, 64-thread blocks
    fused_kernel<<<grid, 64, 0, stream>>>(x, prep1, prep2, sigma_, wmap, num);
    dim3 gridD(HIMG/16, HIMG/16, NIMG);
    final_kernel<<<gridD, 256, 0, stream>>>(num, wmap, out);
}

// Round 13
// 586.980 us; speedup vs baseline: 5.8179x; 1.0302x over previous
//
#include <hip/hip_runtime.h>
#include <math.h>

#define P    13
#define PP   169
#define NIMG 4
#define HIMG 256
#define HP   280            // 256 + 2*12
#define HO   268            // 280 - 13 + 1

typedef __attribute__((ext_vector_type(8))) short short8_t;
typedef __attribute__((ext_vector_type(4))) float f32x4;

__device__ __forceinline__ ushort f2bf(float x) {
    union { float f; unsigned u; } a; a.f = x;
    unsigned r = a.u + 0x7fffu + ((a.u >> 16) & 1u);   // RNE
    return (ushort)(r >> 16);
}
__device__ __forceinline__ float bf2f(ushort b) {
    union { float f; unsigned u; } a; a.u = ((unsigned)b) << 16;
    return a.f;
}

// ---------------- prep1: Pm1 -> MFMA frag layout (plain K), split bf16 hi/lo (verified) ----------------
__global__ __launch_bounds__(256) void prep1_kernel(const float* __restrict__ Pm1,
                                                    ushort* __restrict__ prep1) {
    int idx = blockIdx.x*256 + threadIdx.x;
    if (idx >= 6*11*512) return;
    int j    = idx & 7;
    int lane = (idx >> 3) & 63;
    int rest = idx >> 9;
    int mt   = rest % 11;
    int ks   = rest / 11;
    int row  = mt*16 + (lane & 15);
    int k    = ks*32 + 8*(lane>>4) + j;
    float val = (row < PP && k < PP) ? Pm1[row*PP + k] : 0.0f;
    ushort h = f2bf(val);
    ushort lo = f2bf(val - bf2f(h));
    prep1[((ks*2+0)*11 + mt)*512 + lane*8 + j] = h;
    prep1[((ks*2+1)*11 + mt)*512 + lane*8 + j] = lo;
}

// ---------------- invert: no-pivot register-blocked Gauss-Jordan (VERBATIM verified R11) ----------------
__global__ __launch_bounds__(512, 1) void invert_kernel(const float* __restrict__ Pm1,
                                                        ushort* __restrict__ prep2) {
    extern __shared__ float sm[];
    float* Adump = sm;                      // 169*192 = 32448
    float* dcolB = sm + 32448;              // 2*192
    float* prowB = dcolB + 384;             // 2*192

    int tid = threadIdx.x;
    int ti = tid >> 4, tj = tid & 15;
    int row0 = 6*ti;

    float a[6][12];
#pragma unroll
    for (int m = 0; m < 6; ++m)
#pragma unroll
      for (int u = 0; u < 12; ++u) {
        int i = row0 + m, kc = 11*tj + u;
        a[m][u] = (i < PP && u < 11 && kc < PP) ? Pm1[i*PP + kc] : 0.0f;
      }
    __syncthreads();

    for (int k = 0; k < PP; ++k) {
        int par = k & 1;
        float* dcol = dcolB + par*192;
        float* prow = prowB + par*192;
        int gk = (k*5958) >> 16;            // k/11
        int uk = k - 11*gk;
        int tik = (k*10923) >> 16;          // k/6
        int mk = k - 6*tik;

        if (tj == gk) {
#pragma unroll
            for (int m = 0; m < 6; ++m) {
                float v = a[m][0];
#pragma unroll
                for (int u = 1; u < 12; ++u) v = (u == uk) ? a[m][u] : v;
                dcol[row0 + m] = v;
            }
        }
        if (ti == tik) {
#pragma unroll
            for (int m = 0; m < 6; ++m) if (m == mk) {
#pragma unroll
                for (int u4 = 0; u4 < 3; ++u4) {
                    float4 v4; v4.x=a[m][4*u4]; v4.y=a[m][4*u4+1]; v4.z=a[m][4*u4+2]; v4.w=a[m][4*u4+3];
                    *reinterpret_cast<float4*>(&prow[12*tj + 4*u4]) = v4;
                }
            }
        }
        __syncthreads();   // the ONE barrier

        float pv = dcol[k];
        float invpv = 1.0f / pv;
        float4 p0 = *reinterpret_cast<float4*>(&prow[12*tj]);
        float4 p1 = *reinterpret_cast<float4*>(&prow[12*tj + 4]);
        float4 p2 = *reinterpret_cast<float4*>(&prow[12*tj + 8]);
        float pr[12] = {p0.x,p0.y,p0.z,p0.w, p1.x,p1.y,p1.z,p1.w, p2.x,p2.y,p2.z,p2.w};
        bool myg = (tj == gk);
        float strue[12], supd[12];
#pragma unroll
        for (int u = 0; u < 12; ++u) {
            bool isuk = myg && (u == uk);
            float sv = pr[u] * invpv;
            strue[u] = isuk ? invpv : sv;
            supd[u]  = isuk ? (invpv + 1.0f) : sv;
        }
        float d[6];
#pragma unroll
        for (int m = 0; m < 6; ++m) d[m] = dcol[row0 + m];
#pragma unroll
        for (int m = 0; m < 6; ++m)
#pragma unroll
          for (int u = 0; u < 12; ++u)
            a[m][u] = __builtin_fmaf(-d[m], supd[u], a[m][u]);
        if (ti == tik) {
#pragma unroll
            for (int m = 0; m < 6; ++m) if (m == mk) {
#pragma unroll
                for (int u = 0; u < 12; ++u) a[m][u] = strue[u];
            }
        }
    }
    __syncthreads();

#pragma unroll
    for (int m = 0; m < 6; ++m) {
        int i = row0 + m;
        if (i < PP) {
#pragma unroll
            for (int u4 = 0; u4 < 3; ++u4) {
                float4 v; v.x = a[m][4*u4]; v.y = a[m][4*u4+1]; v.z = a[m][4*u4+2]; v.w = a[m][4*u4+3];
                *reinterpret_cast<float4*>(&Adump[i*192 + 12*tj + 4*u4]) = v;
            }
        }
    }
    __syncthreads();
    for (int o = tid; o < 6*2*11*512; o += 512) {
        int li = o & 511;
        int rest = o >> 9;
        int mt = rest % 11;
        int kp = rest / 11;
        int plane = kp & 1, ks = kp >> 1;
        int lane = li >> 3, j = li & 7;
        int row = mt*16 + (lane & 15);
        int kk = ks*32 + 8*(lane>>4) + j;
        float val = 0.0f;
        if (row < PP && kk < PP) {
            int g = (kk*5958) >> 16;
            val = Adump[row*192 + g*12 + (kk - 11*g)];
        }
        ushort h = f2bf(val);
        prep2[o] = plane ? f2bf(val - bf2f(h)) : h;
    }
}

// ---------------- fused: R12 structure + explicit double-buffered A prefetch ----------------
__device__ __forceinline__ f32x4 mfma3(short8_t ah, short8_t al, short8_t bh, short8_t bl, f32x4 acc) {
    acc = __builtin_amdgcn_mfma_f32_16x16x32_bf16(ah, bh, acc, 0, 0, 0);
    acc = __builtin_amdgcn_mfma_f32_16x16x32_bf16(al, bh, acc, 0, 0, 0);
    acc = __builtin_amdgcn_mfma_f32_16x16x32_bf16(ah, bl, acc, 0, 0, 0);
    return acc;
}

// GEMM1 step: prefetch ks+1 (both planes) into NXT bank, build B, consume CUR bank.
#define G1_STEP(KS, CH, CL, NH, NL, DOPRE) { \
    if (DOPRE) { \
        _Pragma("unroll") \
        for (int mt = 0; mt < 11; ++mt) { \
            NH[mt] = p1v[((2*((KS)+1)+0)*11 + mt)*64 + l]; \
            NL[mt] = p1v[((2*((KS)+1)+1)*11 + mt)*64 + l]; \
        } \
    } \
    short8_t bh, bl; \
    _Pragma("unroll") \
    for (int j = 0; j < 8; ++j) { \
        int k = (KS)*32 + 8*q + j; \
        float v = 0.0f; \
        if (k < PP) { int di = (k*5042) >> 16; int dj = k - 13*di; v = xr[di*28 + c + dj]; } \
        ushort h = f2bf(v); \
        bh[j] = (short)h; \
        bl[j] = (short)f2bf(v - bf2f(h)); \
    } \
    _Pragma("unroll") \
    for (int mt = 0; mt < 11; ++mt) acc[mt] = mfma3(CH[mt], CL[mt], bh, bl, acc[mt]); \
}

// GEMM2 step: prefetch ks+1 ah-plane into NXT, batch-load current al-plane, shuffle B, consume.
#define G2_STEP(KS, CH, NH, DOPRE) { \
    if (DOPRE) { \
        _Pragma("unroll") \
        for (int mt = 0; mt < 11; ++mt) NH[mt] = p2v[((2*((KS)+1)+0)*11 + mt)*64 + l]; \
    } \
    short8_t alc[11]; \
    _Pragma("unroll") \
    for (int mt = 0; mt < 11; ++mt) alc[mt] = p2v[((2*(KS)+1)*11 + mt)*64 + l]; \
    union { short8_t s; uint dd[4]; } BH, BL; \
    _Pragma("unroll") \
    for (int jp = 0; jp < 4; ++jp) { \
        int s2 = ((2*q + (jp >> 1)) & 3)*16 + c; \
        uint ah0 = __shfl(pk_h[2*(KS)    ][jp & 1], s2, 64); \
        uint ah1 = __shfl(pk_h[2*(KS) + 1][jp & 1], s2, 64); \
        uint al0 = __shfl(pk_l[2*(KS)    ][jp & 1], s2, 64); \
        uint al1 = __shfl(pk_l[2*(KS) + 1][jp & 1], s2, 64); \
        BH.dd[jp] = (q >= 2) ? ah1 : ah0; \
        BL.dd[jp] = (q >= 2) ? al1 : al0; \
    } \
    _Pragma("unroll") \
    for (int mt = 0; mt < 11; ++mt) rec[mt] = mfma3(CH[mt], alc[mt], BH.s, BL.s, rec[mt]); \
}

__global__ __launch_bounds__(64, 2) void fused_kernel(
    const float* __restrict__ x,
    const ushort* __restrict__ prep1,
    const ushort* __restrict__ prep2,
    const float* __restrict__ sigma_,
    float* __restrict__ wmap,
    float* __restrict__ num)
{
    __shared__ float xr[13*28];     // staged x region (reflect-pad + affine)
    __shared__ float fp[13*28];     // fold footprint

    int l = threadIdx.x;
    int q = l >> 4, c = l & 15;
    int n = blockIdx.z;
    int ho = blockIdx.y;
    int wo0 = blockIdx.x * 16;
    float lam = 6.0f * sigma_[0];
    const float* xn = x + n*HIMG*HIMG;
    const short8_t* p1v = reinterpret_cast<const short8_t*>(prep1);
    const short8_t* p2v = reinterpret_cast<const short8_t*>(prep2);

    // ---- stage xr + zero fp ----
    for (int idx = l; idx < 364; idx += 64) {
        int i = (idx*2341) >> 16;                 // idx/28 (exact for idx<812)
        int j = idx - i*28;
        int gi = ho + i - 12;
        gi = (gi < 0) ? -gi : gi; gi = (gi > HIMG-1) ? (2*(HIMG-1) - gi) : gi;
        int gj = wo0 + j - 12;
        gj = (gj < 0) ? -gj : gj; gj = (gj > HIMG-1) ? (2*(HIMG-1) - gj) : gj;
        xr[idx] = 2.0f * xn[gi*HIMG + gj] - 1.0f;
        fp[idx] = 0.0f;
    }
    __syncthreads();

    // ---- GEMM1: software-pipelined A (double-buffered banks) ----
    f32x4 acc[11];
#pragma unroll
    for (int mt = 0; mt < 11; ++mt) acc[mt] = (f32x4){0.f,0.f,0.f,0.f};

    short8_t Ah0[11], Al0[11], Ah1[11], Al1[11];
#pragma unroll
    for (int mt = 0; mt < 11; ++mt) {
        Ah0[mt] = p1v[(0*11 + mt)*64 + l];
        Al0[mt] = p1v[(1*11 + mt)*64 + l];
    }
    G1_STEP(0, Ah0, Al0, Ah1, Al1, true)
    G1_STEP(1, Ah1, Al1, Ah0, Al0, true)
    G1_STEP(2, Ah0, Al0, Ah1, Al1, true)
    G1_STEP(3, Ah1, Al1, Ah0, Al0, true)
    G1_STEP(4, Ah0, Al0, Ah1, Al1, true)
    G1_STEP(5, Ah1, Al1, Ah0, Al0, false)

    // ---- threshold + count + pack t into registers ----
    int cadd = 0;
    uint pk_h[12][2], pk_l[12][2];
    pk_h[11][0] = 0u; pk_h[11][1] = 0u; pk_l[11][0] = 0u; pk_l[11][1] = 0u;
#pragma unroll
    for (int mt = 0; mt < 11; ++mt) {
#pragma unroll
        for (int d = 0; d < 2; ++d) {
            ushort th2[2], tl2[2];
#pragma unroll
            for (int e2 = 0; e2 < 2; ++e2) {
                int e = 2*d + e2;
                int r = mt*16 + 4*q + e;
                float dd = acc[mt][e] / lam;
                bool keep = fabsf(dd) > 1.0f;
                float tv = keep ? dd*lam : 0.0f;
                cadd += (keep && r > 0 && r < PP) ? 1 : 0;
                th2[e2] = f2bf(tv);
                tl2[e2] = f2bf(tv - bf2f(th2[e2]));
            }
            pk_h[mt][d] = (uint)th2[0] | ((uint)th2[1] << 16);
            pk_l[mt][d] = (uint)tl2[0] | ((uint)tl2[1] << 16);
        }
    }
    cadd += __shfl_xor(cadd, 16);
    cadd += __shfl_xor(cadd, 32);
    int wo = wo0 + c;
    float wgt = (wo < HO) ? 1.0f / (1.0f + (float)cadd) : 0.0f;
    if (q == 0 && wo < HO) wmap[(n*HO + ho)*HO + wo] = wgt;

    // ---- GEMM2: software-pipelined A (ah prefetch; al batch-loaded per step) ----
    f32x4 rec[11];
#pragma unroll
    for (int mt = 0; mt < 11; ++mt) rec[mt] = (f32x4){0.f,0.f,0.f,0.f};
#pragma unroll
    for (int mt = 0; mt < 11; ++mt) Ah0[mt] = p2v[(0*11 + mt)*64 + l];
    G2_STEP(0, Ah0, Ah1, true)
    G2_STEP(1, Ah1, Ah0, true)
    G2_STEP(2, Ah0, Ah1, true)
    G2_STEP(3, Ah1, Ah0, true)
    G2_STEP(4, Ah0, Ah1, true)
    G2_STEP(5, Ah1, Ah0, false)

    // ---- fold into LDS footprint ----
#pragma unroll
    for (int mt = 0; mt < 11; ++mt) {
#pragma unroll
        for (int e = 0; e < 4; ++e) {
            int r = mt*16 + 4*q + e;
            if (r < PP) {
                int di = (r*5042) >> 16;              // r/13
                int dj = r - 13*di;
                atomicAdd(&fp[di*28 + c + dj], rec[mt][e] * wgt);
            }
        }
    }
    __syncthreads();

    // ---- flush: 364 global atomics per block ----
    float* nump = num + n*HP*HP;
    for (int idx = l; idx < 364; idx += 64) {
        int i = (idx*2341) >> 16;
        int j = idx - i*28;
        int gy = ho + i, gx = wo0 + j;
        if (gx < HP) atomicAdd(&nump[gy*HP + gx], fp[idx]);
    }
}

// ---------------- final: out = (num / box13(w) + 1)/2 (verified) ----------------
__global__ __launch_bounds__(256) void final_kernel(const float* __restrict__ num,
                                                    const float* __restrict__ wmap,
                                                    float* __restrict__ out)
{
    __shared__ float wr[28][28];
    int tid = threadIdx.x;
    int n = blockIdx.z;
    int y0 = blockIdx.y * 16, x0 = blockIdx.x * 16;
    const float* wp = wmap + n*HO*HO;
    for (int idx = tid; idx < 28*28; idx += 256) {
        int i = idx / 28, j = idx - (idx/28)*28;
        wr[i][j] = wp[(y0 + i)*HO + (x0 + j)];
    }
    __syncthreads();
    int py = tid >> 4, px = tid & 15;
    float dv = 0.0f;
#pragma unroll
    for (int a = 0; a < 13; ++a)
#pragma unroll
        for (int b = 0; b < 13; ++b)
            dv += wr[py + a][px + b];
    int y = y0 + py, x = x0 + px;
    float nv = num[(n*HP + (y + 12))*HP + (x + 12)];
    out[(n*HIMG + y)*HIMG + x] = (nv / dv + 1.0f) * 0.5f;
}

extern "C" void kernel_launch(void* const* d_in, const int* in_sizes, int n_in,
                              void* d_out, int out_size, void* d_ws, size_t ws_size,
                              hipStream_t stream) {
    const float* x      = (const float*)d_in[0];
    const float* sigma_ = (const float*)d_in[1];
    const float* Pm1    = (const float*)d_in[2];
    float* ws    = (float*)d_ws;
    float* wmap  = ws;                           // 287,296 f
    float* num   = ws + 287296;                  // 313,600 f
    ushort* prep1 = (ushort*)(ws + 600896);      // 67,584 ushorts
    ushort* prep2 = (ushort*)(ws + 634688);      // 67,584 ushorts
    float* out   = (float*)d_out;

    const int INV_LDS = (32448 + 2*384) * 4;     // 132,864 B
    hipFuncSetAttribute((const void*)invert_kernel, hipFuncAttributeMaxDynamicSharedMemorySize, INV_LDS);

    hipMemsetAsync(num, 0, (size_t)NIMG*HP*HP*sizeof(float), stream);
    prep1_kernel<<<(6*11*512 + 255)/256, 256, 0, stream>>>(Pm1, prep1);
    invert_kernel<<<1, 512, INV_LDS, stream>>>(Pm1, prep2);
    dim3 grid((HO + 15)/16, HO, NIMG);           // 17 x 268 x 4, 64-thread blocks
    fused_kernel<<<grid, 64, 0, stream>>>(x, prep1, prep2, sigma_, wmap, num);
    dim3 gridD(HIMG/16, HIMG/16, NIMG);
    final_kernel<<<gridD, 256, 0, stream>>>(num, wmap, out);
}